// Round 6
// baseline (227.307 us; speedup 1.0000x reference)
//
#include <hip/hip_runtime.h>
#include <math.h>

typedef __bf16 bf16x8 __attribute__((ext_vector_type(8)));
typedef float  f32x4  __attribute__((ext_vector_type(4)));
typedef unsigned short us4 __attribute__((ext_vector_type(4)));

constexpr int N_EMBD = 1024;
constexpr int T_SEQ  = 128;
constexpr int HS     = 128;
constexpr int BATCH  = 256;

__device__ __forceinline__ void async16(const void* g, void* l) {
    __builtin_amdgcn_global_load_lds(
        (const __attribute__((address_space(1))) unsigned int*)g,
        (__attribute__((address_space(3))) unsigned int*)l, 16, 0, 0);
}
__device__ __forceinline__ unsigned short bfbits(float f) {
    return __builtin_bit_cast(unsigned short, (__bf16)f);
}
__device__ __forceinline__ f32x4 zero4() {
    f32x4 z = {0.f, 0.f, 0.f, 0.f};
    return z;
}

// ---------------- Kernel 0: W cast + transpose ----------------
__global__ __launch_bounds__(256) void wcast(
    const float* __restrict__ Wq, const float* __restrict__ Wk,
    const float* __restrict__ Wv, unsigned short* __restrict__ Wt)
{
    __shared__ unsigned short tile[64][130];
    const int bid = blockIdx.x;
    const int nt  = bid >> 4;
    const int k0  = (bid & 15) << 6;
    const float* src = (nt == 0) ? Wq : ((nt == 1) ? Wk : Wv);
    const int tid = threadIdx.x;
#pragma unroll
    for (int j = 0; j < 32; ++j) {
        int idx = tid + j * 256;
        int k = idx >> 7, n = idx & 127;
        tile[k][n] = bfbits(src[(size_t)(k0 + k) * HS + n]);
    }
    __syncthreads();
#pragma unroll
    for (int j = 0; j < 32; ++j) {
        int idx = tid + j * 256;
        int n = idx >> 6, kk = idx & 63;
        Wt[(size_t)(nt * 128 + n) * N_EMBD + k0 + kk] = tile[kk][n];
    }
}

// ---------------- Kernel 1: fully fused head, one block per batch ----------------
// 256 blocks x 512 threads (8 waves), 1 block/CU, LDS 136 KB.
// Phase 1 (QKV GEMM, M=128 N=384 K=1024, BK=64, DOUBLE-BUFFERED):
//   A (x fp32): global->reg ping-pong (issued 2 chunks ahead = full-iter latency
//   budget) -> cvt bf16 -> ds_write_b128 into Ab[nxt]. B (Wt bf16): async16 into
//   Bb[nxt], issued before compute so the barrier drain overlaps 48 MFMA/wave.
//   Both LDS arrays XOR-swizzled: slot = chunk ^ (row&7) -> 2-way max conflicts.
// Phase 2: RoPE epilogue -> q/k/v in LDS -> per-wave causal attention (round-5
// verified code), out fp32.
__global__ __launch_bounds__(512, 2) void head_fused(
    const float* __restrict__ x,
    const unsigned short* __restrict__ Wt,
    float* __restrict__ out)
{
    __shared__ char lds[139264];
    // phase-1 layout
    constexpr int AB0 = 0,     AB1 = 16384;    // 128 rows x 128 B (64 bf16)
    constexpr int BB0 = 32768, BB1 = 81920;    // 384 rows x 128 B
    // phase-2 layout (reuses everything)
    constexpr int QS = 0;          // 128 x 272 B
    constexpr int KS = 34816;
    constexpr int VS = 69632;      // v as [d][s]
    constexpr int PS = 104448;     // 8 waves x 16 rows x 272 B

    const int tid  = threadIdx.x;
    const int w    = tid >> 6;
    const int l    = tid & 63;
    const int cl   = l & 15;
    const int quad = l >> 4;
    const int b    = blockIdx.x;
    const int row0 = b << 7;
    const int wm   = (w & 1) << 6;     // 0 / 64
    const int wn   = (w >> 1) * 96;    // 0,96,192,288

    // A: thread -> row tid>>2, 16-float segment (tid&3)*16
    const int arow = tid >> 2;
    const int acq  = tid & 3;
    const float* aptr = x + (size_t)(row0 + arow) * N_EMBD + acq * 16;
    const int as0 = (acq * 2) ^ (arow & 7);        // swizzled 16B-slot indices
    const int as1 = (acq * 2 + 1) ^ (arow & 7);
    // B: per-wave async16 rows
    const int brow_lo = l >> 3;                    // 0..7
    const int bswz = ((l & 7) ^ (l >> 3)) * 8;     // source col offset (elements)

    f32x4 acc[4][6];
#pragma unroll
    for (int a = 0; a < 4; ++a)
#pragma unroll
        for (int c = 0; c < 6; ++c) acc[a][c] = zero4();

    f32x4 ar[2][4];

#define LOAD_A(set, chunk)                                             \
    do {                                                               \
        const float* p_ = aptr + (chunk) * 64;                         \
        ar[set][0] = *(const f32x4*)(p_);                              \
        ar[set][1] = *(const f32x4*)(p_ + 4);                          \
        ar[set][2] = *(const f32x4*)(p_ + 8);                          \
        ar[set][3] = *(const f32x4*)(p_ + 12);                         \
    } while (0)

#define STAGE_A(dst, set)                                              \
    do {                                                               \
        bf16x8 w0_, w1_;                                               \
        w0_[0] = (__bf16)ar[set][0][0]; w0_[1] = (__bf16)ar[set][0][1];\
        w0_[2] = (__bf16)ar[set][0][2]; w0_[3] = (__bf16)ar[set][0][3];\
        w0_[4] = (__bf16)ar[set][1][0]; w0_[5] = (__bf16)ar[set][1][1];\
        w0_[6] = (__bf16)ar[set][1][2]; w0_[7] = (__bf16)ar[set][1][3];\
        w1_[0] = (__bf16)ar[set][2][0]; w1_[1] = (__bf16)ar[set][2][1];\
        w1_[2] = (__bf16)ar[set][2][2]; w1_[3] = (__bf16)ar[set][2][3];\
        w1_[4] = (__bf16)ar[set][3][0]; w1_[5] = (__bf16)ar[set][3][1];\
        w1_[6] = (__bf16)ar[set][3][2]; w1_[7] = (__bf16)ar[set][3][3];\
        *(bf16x8*)(lds + (dst) + arow * 128 + (as0 << 4)) = w0_;       \
        *(bf16x8*)(lds + (dst) + arow * 128 + (as1 << 4)) = w1_;       \
    } while (0)

#define ASYNC_B(dst, chunk)                                            \
    do {                                                               \
        _Pragma("unroll")                                              \
        for (int jj_ = 0; jj_ < 6; ++jj_) {                            \
            int j_ = w * 6 + jj_;                                      \
            int n_ = j_ * 8 + brow_lo;                                 \
            async16(Wt + (size_t)n_ * N_EMBD + (chunk) * 64 + bswz,    \
                    lds + (dst) + j_ * 1024);                          \
        }                                                              \
    } while (0)

#define COMPUTE(ca, cb)                                                \
    do {                                                               \
        _Pragma("unroll")                                              \
        for (int ks_ = 0; ks_ < 2; ++ks_) {                            \
            const int kq_ = ks_ * 4 + quad;                            \
            bf16x8 af_[4], bf_[6];                                     \
            _Pragma("unroll")                                          \
            for (int rt_ = 0; rt_ < 4; ++rt_) {                        \
                int m_ = wm + rt_ * 16 + cl;                           \
                af_[rt_] = *(const bf16x8*)(lds + (ca) + m_ * 128 +    \
                                            ((kq_ ^ (m_ & 7)) << 4));  \
            }                                                          \
            _Pragma("unroll")                                          \
            for (int ct_ = 0; ct_ < 6; ++ct_) {                        \
                int n_ = wn + ct_ * 16 + cl;                           \
                bf_[ct_] = *(const bf16x8*)(lds + (cb) + n_ * 128 +    \
                                            ((kq_ ^ (n_ & 7)) << 4));  \
            }                                                          \
            _Pragma("unroll")                                          \
            for (int rt_ = 0; rt_ < 4; ++rt_)                          \
                _Pragma("unroll")                                      \
                for (int ct_ = 0; ct_ < 6; ++ct_)                      \
                    acc[rt_][ct_] = __builtin_amdgcn_mfma_f32_16x16x32_bf16( \
                        af_[rt_], bf_[ct_], acc[rt_][ct_], 0, 0, 0);   \
        }                                                              \
    } while (0)

    // prologue: chunk 0 staged, chunk 1 in regs
    LOAD_A(0, 0);
    STAGE_A(AB0, 0);
    ASYNC_B(BB0, 0);
    LOAD_A(1, 1);
    __syncthreads();

#pragma unroll
    for (int it = 0; it < 16; ++it) {
        const int curA = (it & 1) ? AB1 : AB0;
        const int nxtA = (it & 1) ? AB0 : AB1;
        const int curB = (it & 1) ? BB1 : BB0;
        const int nxtB = (it & 1) ? BB0 : BB1;
        if (it < 15) {
            ASYNC_B(nxtB, it + 1);          // issued first: drains under compute
            STAGE_A(nxtA, (it + 1) & 1);    // regs loaded a full iter ago
            if (it < 14) LOAD_A(it & 1, it + 2);   // 2 chunks ahead
        }
        COMPUTE(curA, curB);
        __syncthreads();
    }

    // ---- epilogue: RoPE + q/k/v -> LDS ----
    const float LNT = 0.07195578430905272f;   // ln(10000)/128
#pragma unroll
    for (int ct = 0; ct < 6; ++ct) {
        int c0  = wn + ct * 16;
        int ntc = c0 >> 7;                    // 0=q 1=k 2=v, uniform per tile
        int d   = (c0 & 127) + cl;
        if (ntc < 2) {
            int qk = (ntc == 0) ? QS : KS;
            float freq = __expf(-(float)(d & ~1) * LNT);
#pragma unroll
            for (int rt = 0; rt < 4; ++rt) {
#pragma unroll
                for (int i = 0; i < 4; ++i) {
                    int t = wm + rt * 16 + quad * 4 + i;
                    float v = acc[rt][ct][i];
                    float p = __shfl_xor(v, 1);
                    float sn, cs;
                    __sincosf((float)t * freq, &sn, &cs);
                    float r = ((d & 1) == 0) ? (v * cs - p * sn) : (p * sn + v * cs);
                    *(unsigned short*)(lds + qk + t * 272 + d * 2) = bfbits(r);
                }
            }
        } else {
#pragma unroll
            for (int rt = 0; rt < 4; ++rt) {
                int s0 = wm + rt * 16 + quad * 4;
                us4 u;
                u.x = bfbits(acc[rt][ct][0]);
                u.y = bfbits(acc[rt][ct][1]);
                u.z = bfbits(acc[rt][ct][2]);
                u.w = bfbits(acc[rt][ct][3]);
                *(us4*)(lds + VS + d * 272 + s0 * 2) = u;
            }
        }
    }
    __syncthreads();   // q/k/v visible to all waves

    // ---- phase 2: causal attention, wave w owns Q rows [w*16, w*16+16) ----
    const int nct = w + 1;
    const int nks = (w + 2) >> 1;
    char* pl = lds + PS + w * 4352;

    bf16x8 qf[4];
#pragma unroll
    for (int ks = 0; ks < 4; ++ks)
        qf[ks] = *(const bf16x8*)(lds + QS + (w * 16 + cl) * 272 + (ks * 4 + quad) * 16);

    f32x4 s[8];
#pragma unroll
    for (int ct = 0; ct < 8; ++ct) s[ct] = zero4();

#pragma unroll
    for (int ct = 0; ct < 8; ++ct) if (ct < nct) {
        const char* kr = lds + KS + (ct * 16 + cl) * 272;
#pragma unroll
        for (int ks = 0; ks < 4; ++ks) {
            bf16x8 bb = *(const bf16x8*)(kr + (ks * 4 + quad) * 16);
            s[ct] = __builtin_amdgcn_mfma_f32_16x16x32_bf16(qf[ks], bb, s[ct], 0, 0, 0);
        }
    }

    const float scale = 0.08838834764831845f;   // 1/sqrt(128)
#pragma unroll
    for (int i = 0; i < 4; ++i) {
        int t = w * 16 + quad * 4 + i;
        float mx = -3.0e38f;
#pragma unroll
        for (int ct = 0; ct < 8; ++ct) if (ct < nct) {
            int col = ct * 16 + cl;
            float v = s[ct][i] * scale;
            v = (col <= t) ? v : -INFINITY;
            s[ct][i] = v;
            mx = fmaxf(mx, v);
        }
        mx = fmaxf(mx, __shfl_xor(mx, 1));
        mx = fmaxf(mx, __shfl_xor(mx, 2));
        mx = fmaxf(mx, __shfl_xor(mx, 4));
        mx = fmaxf(mx, __shfl_xor(mx, 8));
        float sum = 0.f;
#pragma unroll
        for (int ct = 0; ct < 8; ++ct) if (ct < nct) {
            float p = __expf(s[ct][i] - mx);
            s[ct][i] = p;
            sum += p;
        }
        sum += __shfl_xor(sum, 1);
        sum += __shfl_xor(sum, 2);
        sum += __shfl_xor(sum, 4);
        sum += __shfl_xor(sum, 8);
        float inv = 1.0f / sum;
        int rl = quad * 4 + i;
#pragma unroll
        for (int ct = 0; ct < 8; ++ct) if (ct < nct) {
            *(unsigned short*)(pl + rl * 272 + (ct * 16 + cl) * 2) =
                bfbits(s[ct][i] * inv);
        }
        if ((w & 1) == 0) {   // PV consumes one 16-col tile past the stored range
            *(unsigned short*)(pl + rl * 272 + (nct * 16 + cl) * 2) = 0;
        }
    }
    // same-wave ds_write -> ds_read: compiler inserts lgkmcnt wait; no barrier.

    bf16x8 ap[4];
#pragma unroll
    for (int ks = 0; ks < 4; ++ks) if (ks < nks)
        ap[ks] = *(const bf16x8*)(pl + cl * 272 + (ks * 4 + quad) * 16);

    f32x4 o[8];
#pragma unroll
    for (int ct = 0; ct < 8; ++ct) o[ct] = zero4();

#pragma unroll
    for (int ct = 0; ct < 8; ++ct) {
        const char* vr = lds + VS + (ct * 16 + cl) * 272;
#pragma unroll
        for (int ks = 0; ks < 4; ++ks) if (ks < nks) {
            bf16x8 bb = *(const bf16x8*)(vr + (ks * 4 + quad) * 16);
            o[ct] = __builtin_amdgcn_mfma_f32_16x16x32_bf16(ap[ks], bb, o[ct], 0, 0, 0);
        }
    }

#pragma unroll
    for (int ct = 0; ct < 8; ++ct)
#pragma unroll
        for (int i = 0; i < 4; ++i) {
            int t = w * 16 + quad * 4 + i;
            out[(size_t)b * 16384 + (size_t)t * HS + ct * 16 + cl] = o[ct][i];
        }
#undef LOAD_A
#undef STAGE_A
#undef ASYNC_B
#undef COMPUTE
}

// ---------------- launch ----------------
extern "C" void kernel_launch(void* const* d_in, const int* in_sizes, int n_in,
                              void* d_out, int out_size, void* d_ws, size_t ws_size,
                              hipStream_t stream) {
    const float* x  = (const float*)d_in[0];
    const float* Wq = (const float*)d_in[1];
    const float* Wk = (const float*)d_in[2];
    const float* Wv = (const float*)d_in[3];
    float* out = (float*)d_out;

    unsigned short* Wt = (unsigned short*)d_ws;   // 384 x 1024 bf16 = 768 KB

    wcast<<<48, 256, 0, stream>>>(Wq, Wk, Wv, Wt);
    head_fused<<<BATCH, 512, 0, stream>>>(x, Wt, out);
}